// Round 22
// baseline (194.059 us; speedup 1.0000x reference)
//
#include <hip/hip_runtime.h>
#include <math.h>

#define BATCH 512
#define SEQ   256
#define DIM   256
#define NHEAD 8
#define DFF   1024
#define NT    512   // threads per block (8 waves)
#define NW    8     // waves per block

typedef unsigned short ushort;
typedef unsigned int   uint;
typedef __fp16 half2v __attribute__((ext_vector_type(2)));

// ---------- f16 weight image layout in d_ws (ushort units) ----------
#define OFF_QKV   0u          // 768*256
#define OFF_AO    196608u     // 256*256
#define OFF_FF1   262144u     // 1024*256
#define OFF_FF2   524288u     // 256*1024
#define OFF_RELU  786432u     // 256*256
#define OFF_DT    851968u     // 256*256
#define OFF_ZN    917504u     // 257*257
#define OFF_A0    983553u     // 277*277
#define OFF_A1    1060282u    // 277*277
#define OFF_KT    1137011u    // WkT: 256 d-rows x 256 k  (transposed Wk)
#define CVT_TOTAL 1202547u

// ---------- weight conversion kernel (runs every launch; deterministic) ----------
__global__ __launch_bounds__(512) void cvt_weights(
    const float* __restrict__ qkv, const float* __restrict__ ao,
    const float* __restrict__ ff1, const float* __restrict__ ff2,
    const float* __restrict__ relu, const float* __restrict__ dT,
    const float* __restrict__ zn, const float* __restrict__ a0,
    const float* __restrict__ a1, ushort* __restrict__ ws) {
  uint i = blockIdx.x * 512u + threadIdx.x;
  if (i >= CVT_TOTAL) return;
  float v;
  if (i >= OFF_KT) {
    uint idx = i - OFF_KT;
    uint d = idx >> 8, k = idx & 255u;
    v = qkv[(size_t)(256 + k) * 256 + d];   // WkT[d][k] = Wk[k][d]
  } else {
    const float* src; uint off;
    if      (i < OFF_AO)  { src = qkv;  off = OFF_QKV; }
    else if (i < OFF_FF1) { src = ao;   off = OFF_AO; }
    else if (i < OFF_FF2) { src = ff1;  off = OFF_FF1; }
    else if (i < OFF_RELU){ src = ff2;  off = OFF_FF2; }
    else if (i < OFF_DT)  { src = relu; off = OFF_RELU; }
    else if (i < OFF_ZN)  { src = dT;   off = OFF_DT; }
    else if (i < OFF_A0)  { src = zn;   off = OFF_ZN; }
    else if (i < OFF_A1)  { src = a0;   off = OFF_A0; }
    else                  { src = a1;   off = OFF_A1; }
    v = src[i - off];
  }
  __fp16 h = (__fp16)v;          // RNE
  union { __fp16 h; ushort u; } c; c.h = h;
  ws[i] = c.u;
}

// ---------- helpers ----------

__device__ __forceinline__ half2v u2h(uint u) {
  union { uint u; half2v h; } c; c.u = u; return c.h;
}

__device__ __forceinline__ float wave_allred(float v) {
  #pragma unroll
  for (int off = 32; off > 0; off >>= 1) v += __shfl_xor(v, off, 64);
  return v;
}

// Reduce 4 independent partials over a full wave. 16-lane group g = lane>>4
// holds value [0,2,1,3][g].
__device__ __forceinline__ float fold4(int lane, float p0, float p1, float p2, float p3) {
  float za = (lane & 32) ? p1 : p0;
  float ta = (lane & 32) ? p0 : p1;
  za += __shfl_xor(ta, 32, 64);
  float zb = (lane & 32) ? p3 : p2;
  float tb = (lane & 32) ? p2 : p3;
  zb += __shfl_xor(tb, 32, 64);
  float u = (lane & 16) ? zb : za;
  float t = (lane & 16) ? za : zb;
  u += __shfl_xor(t, 16, 64);
  u += __shfl_xor(u, 8, 64);
  u += __shfl_xor(u, 4, 64);
  u += __shfl_xor(u, 2, 64);
  u += __shfl_xor(u, 1, 64);
  return u;
}

// Reduce 4 partials WITHIN each 32-lane half (7 shuffles).
// 8-lane group g=(lane>>3)&3 holds value iv = ((g&1)<<1) | ((g>>1)&1).
__device__ __forceinline__ float fold4h(int lane, const float p[4]) {
  float z0 = (lane & 16) ? p[1] : p[0], y0 = (lane & 16) ? p[0] : p[1];
  z0 += __shfl_xor(y0, 16, 64);
  float z1 = (lane & 16) ? p[3] : p[2], y1 = (lane & 16) ? p[2] : p[3];
  z1 += __shfl_xor(y1, 16, 64);
  float u = (lane & 8) ? z1 : z0, t = (lane & 8) ? z0 : z1;
  u += __shfl_xor(t, 8, 64);
  u += __shfl_xor(u, 4, 64);
  u += __shfl_xor(u, 2, 64);
  u += __shfl_xor(u, 1, 64);
  return u;
}

// Writer lanes for a W4 burst: (lane&7)==0; row = base + (lane>>5)*4 + iv
__device__ __forceinline__ bool burst_writer4(int lane, int& row_off) {
  if (lane & 7) return false;
  int g = (lane >> 3) & 3;
  int iv = ((g & 1) << 1) | ((g >> 1) & 1);
  row_off = ((lane >> 5) << 2) + iv;
  return true;
}

struct XH { half2v h[4]; };   // 8 f16 activations, 4 VGPRs

__device__ __forceinline__ XH ldx8h(const float* __restrict__ x, int lane) {
  int k = (lane & 31) * 8;
  XH r;
  r.h[0] = __builtin_amdgcn_cvt_pkrtz(x[k],     x[k + 1]);
  r.h[1] = __builtin_amdgcn_cvt_pkrtz(x[k + 2], x[k + 3]);
  r.h[2] = __builtin_amdgcn_cvt_pkrtz(x[k + 4], x[k + 5]);
  r.h[3] = __builtin_amdgcn_cvt_pkrtz(x[k + 6], x[k + 7]);
  return r;
}

// 8 f16 weights (uint4) . 8 f16 activations via 4x v_dot2_f32_f16
__device__ __forceinline__ void accum1(uint4 w, const XH& x, float& p) {
  p = __builtin_amdgcn_fdot2(u2h(w.x), x.h[0], p, false);
  p = __builtin_amdgcn_fdot2(u2h(w.y), x.h[1], p, false);
  p = __builtin_amdgcn_fdot2(u2h(w.z), x.h[2], p, false);
  p = __builtin_amdgcn_fdot2(u2h(w.w), x.h[3], p, false);
}

struct W4 { uint4 w[4]; };   // one burst's weights: 4 rows x 16B (16 VGPRs)

// issue 4 row loads (each 32-lane half covers rows (lane>>5)*4 .. +3)
__device__ __forceinline__ W4 ldw4(const ushort* __restrict__ Wb, int ld, int lane) {
  const ushort* wp = Wb + (size_t)((lane >> 5) * 4) * ld + (lane & 31) * 8;
  W4 r;
  #pragma unroll
  for (int i = 0; i < 4; ++i) r.w[i] = *(const uint4*)(wp + (size_t)i * ld);
  return r;
}

__device__ __forceinline__ void accum4(const W4& w, const XH& x, float p[4]) {
  #pragma unroll
  for (int i = 0; i < 4; ++i) accum1(w.w[i], x, p[i]);
}

// block sum over 8 waves; ALL 512 threads must call
__device__ __forceinline__ float block_sum8(float v, float* red) {
  #pragma unroll
  for (int off = 32; off > 0; off >>= 1) v += __shfl_xor(v, off, 64);
  __syncthreads();
  if ((threadIdx.x & 63) == 0) red[threadIdx.x >> 6] = v;
  __syncthreads();
  float s = 0.f;
  #pragma unroll
  for (int i = 0; i < NW; ++i) s += red[i];
  return s;
}

// fused dual block sum (sum, sumsq) -> one barrier pair instead of two
__device__ __forceinline__ void block_sum8x2(float a, float b2, float* red,
                                             float& A, float& B) {
  #pragma unroll
  for (int off = 32; off > 0; off >>= 1) {
    a  += __shfl_xor(a,  off, 64);
    b2 += __shfl_xor(b2, off, 64);
  }
  __syncthreads();
  if ((threadIdx.x & 63) == 0) {
    red[threadIdx.x >> 6] = a;
    red[NW + (threadIdx.x >> 6)] = b2;
  }
  __syncthreads();
  A = 0.f; B = 0.f;
  #pragma unroll
  for (int i = 0; i < NW; ++i) { A += red[i]; B += red[NW + i]; }
}

struct Buf {
  float sc[2048];     // w~ [d][h] -> scores [h][s] -> att [s][h] -> u [h][d] -> ffb -> z1/a0/a1
  float pe[SEQ];
  float srcl[DIM];
  float qv[DIM];      // q -> tv(LN1) -> tv(LN2)
  float ao[DIM];
  float h1[DIM];      // h1 -> d1
  float h2[DIM];
  float xr[DIM];
  float znin[260];
  float fa[280];
  float znv[20];
  float cb[8];
  float scA[9 * 8];
  float scZ[20 * 8];
  float mHJ[8 * 8];
  float biasO8[8];
  float wsum8[8];
  float attA[8 * 9];
  float attZ[8 * 20];
  float oAcc[8 * 7];
  float peAcc8[8];
  int    Xcode[SEQ];      // Xa | (Xz<<8)  (packed: -1KB)
  __fp16 Xoh[SEQ * 7];    // o values are small ints 0..8: exact in f16 (-3.5KB)
};

// ---------- fused kernel: ONE batch element per 512-thread block ----------
// Same 32 waves/CU as R20 (VGPR<=32 => 8 waves/SIMD) but as 4 blocks/CU x
// 8 waves instead of 2 x 16: each __syncthreads convoys only 8 waves, and
// the CU interleaves 4 independent batch pipelines so one block's barrier
// drain is covered by the other three. LDS trimmed to ~36.5KB (packed
// Xa/Xz, f16 Xo - lossless) so 4 blocks fit in 160KB.
// Canary: LDS_Block_Size <= 40960, VGPR ~32.

__global__ __launch_bounds__(NT, 8) void nmstpp_fused(
    const int*   __restrict__ X,
    const float* __restrict__ emb_act,
    const float* __restrict__ emb_zone,
    const float* __restrict__ lin0_w,
    const float* __restrict__ lin0_b,
    const ushort* __restrict__ w16,       // f16 weight image
    const float* __restrict__ qkv_b,
    const float* __restrict__ attn_o_b,
    const float* __restrict__ ln1_g, const float* __restrict__ ln1_b,
    const float* __restrict__ ff1_b,
    const float* __restrict__ ff2_b,
    const float* __restrict__ ln2_g, const float* __restrict__ ln2_b,
    const float* __restrict__ relu_b,
    const float* __restrict__ dT_b,
    const float* __restrict__ lindT_w,
    const float* __restrict__ lindT_b,
    const float* __restrict__ zn_b,
    const float* __restrict__ linzn_w,
    const float* __restrict__ linzn_b,
    const float* __restrict__ act0_b,
    const float* __restrict__ act1_b,
    const float* __restrict__ linact_w,
    const float* __restrict__ linact_b,
    float* __restrict__ out)
{
  const int tid  = threadIdx.x;
  const int wid  = tid >> 6;          // 0..7
  const int lane = tid & 63;
  const int b    = blockIdx.x;
  const int hb4  = (tid >> 8) * 4;    // half -> 4 heads: threads<256 -> 0-3, else 4-7
  const int dd   = tid & 255;         // channel/position for 256-wide split phases

  const ushort* qkv16  = w16 + OFF_QKV;
  const ushort* ao16   = w16 + OFF_AO;
  const ushort* ff116  = w16 + OFF_FF1;
  const ushort* ff216  = w16 + OFF_FF2;
  const ushort* relu16 = w16 + OFF_RELU;
  const ushort* dT16   = w16 + OFF_DT;
  const ushort* kt16   = w16 + OFF_KT;
  const __fp16* znh  = (const __fp16*)(w16 + OFF_ZN);
  const __fp16* a0h  = (const __fp16*)(w16 + OFF_A0);
  const __fp16* a1h  = (const __fp16*)(w16 + OFF_A1);

  __shared__ alignas(16) Buf s;
  __shared__ float embA[9 * 65];
  __shared__ float embZ[20 * 65];
  __shared__ float l0w[128 * 7];
  __shared__ float l0b[128];
  __shared__ float red[2 * NW];

  // ---- phase 0: stage tables + X / pe ----
  for (int i = tid; i < 9 * 64;  i += NT) embA[(i >> 6) * 65 + (i & 63)] = emb_act[i];
  for (int i = tid; i < 20 * 64; i += NT) embZ[(i >> 6) * 65 + (i & 63)] = emb_zone[i];
  for (int i = tid; i < 128 * 7; i += NT) l0w[i] = lin0_w[i];
  if (tid < 128) l0b[tid] = lin0_b[tid];
  if (tid < SEQ) {
    const int* xrow = X + (b * SEQ + tid) * 9;
    s.Xcode[tid] = xrow[0] | (xrow[1] << 8);
    #pragma unroll
    for (int j = 0; j < 7; ++j) s.Xoh[tid * 7 + j] = (__fp16)(float)xrow[2 + j];
    float ex  = (float)(2 * tid) / (float)SEQ;
    float ang = (float)b * exp2f(-ex * 6.643856189774724f);  // 100^-ex
    s.pe[tid] = ((tid & 1) == 0) ? __sinf(ang) : __cosf(ang);
  }
  __syncthreads();

  // ---- phase 1: src at last position ----
  if (tid < DIM) {
    int code = s.Xcode[SEQ - 1];
    int av = code & 255, zv = code >> 8;
    float v;
    if (tid < 64)        v = embA[av * 65 + tid];
    else if (tid < 128)  v = embZ[zv * 65 + (tid - 64)];
    else {
      const float* lr = l0w + (tid - 128) * 7;
      float acc = l0b[tid - 128];
      #pragma unroll
      for (int j = 0; j < 7; ++j) acc = fmaf(lr[j], (float)s.Xoh[(SEQ - 1) * 7 + j], acc);
      v = acc;
    }
    s.srcl[tid] = v + s.pe[SEQ - 1];
  }
  __syncthreads();

  // ---- phase 2: q = Wq @ srcl + bq (4 x 8-row W4 bursts per wave) ----
  {
    XH x = ldx8h(s.srcl, lane);
    #pragma unroll 1
    for (int t = 0; t < 4; ++t) {
      int base = (wid + 8 * t) * 8;
      W4 w = ldw4(qkv16 + (size_t)base * 256, 256, lane);
      float p[4] = {};
      accum4(w, x, p);
      float u = fold4h(lane, p);
      int ro;
      if (burst_writer4(lane, ro)) s.qv[base + ro] = qkv_b[base + ro] + u;
    }
  }
  __syncthreads();

  // ---- phase 3: w~[d][h] via WkT bursts + segmented 4-lane fold ----
  {
    XH x = ldx8h(s.qv, lane);                 // q as f16
    const float inv = 0.17677669529663687f;  // 1/sqrt(32)
    #pragma unroll 1
    for (int t = 0; t < 4; ++t) {
      int base = (wid + 8 * t) * 8;           // 8 d-rows per burst
      W4 w = ldw4(kt16 + (size_t)base * 256, 256, lane);
      float p[4] = {};
      accum4(w, x, p);
      #pragma unroll
      for (int i = 0; i < 4; ++i) {
        p[i] += __shfl_xor(p[i], 1, 4);
        p[i] += __shfl_xor(p[i], 2, 4);
      }
      int sub = lane & 31;
      int h = sub >> 2, jj = sub & 3;
      int dbase = base + ((lane >> 5) << 2);
      s.sc[(dbase + jj) * 8 + h] = p[jj] * inv;
    }
  }
  __syncthreads();

  // ---- phase 3.5: collapse scores into lookup tables ----
  if (tid < 312) {
    if (tid < 296) {
      int h = tid / 37, k = tid - h * 37;
      if (k < 9) {
        float acc = 0.f;
        for (int c = 0; c < 64; ++c) acc = fmaf(s.sc[c * 8 + h], embA[k * 65 + c], acc);
        s.scA[k * 8 + h] = acc;
      } else if (k < 29) {
        int z = k - 9; float acc = 0.f;
        for (int c = 0; c < 64; ++c) acc = fmaf(s.sc[(64 + c) * 8 + h], embZ[z * 65 + c], acc);
        s.scZ[z * 8 + h] = acc;
      } else if (k < 36) {
        int j = k - 29; float acc = 0.f;
        for (int kk = 0; kk < 128; ++kk) acc = fmaf(s.sc[(128 + kk) * 8 + h], l0w[kk * 7 + j], acc);
        s.mHJ[h * 8 + j] = acc;
      } else {
        float acc = 0.f;
        for (int c = 0; c < 256; ++c) acc += s.sc[c * 8 + h];
        s.wsum8[h] = acc;
      }
    } else if (tid < 304) {
      int h = tid - 296; float acc = 0.f;
      for (int kk = 0; kk < 128; ++kk) acc = fmaf(s.sc[(128 + kk) * 8 + h], l0b[kk], acc);
      s.biasO8[h] = acc;
    } else {
      int h = tid - 304; float acc = 0.f;
      for (int c = 0; c < 32; ++c) acc += s.qv[h * 32 + c] * qkv_b[DIM + h * 32 + c];
      s.cb[h] = acc * 0.17677669529663687f;
    }
  }
  __syncthreads();

  // ---- phase 4: scores via tables (thread = (position, head-half)) ----
  {
    const int sp = dd;
    int code = s.Xcode[sp];
    int av = code & 255, zv = code >> 8;
    float o[7];
    #pragma unroll
    for (int j = 0; j < 7; ++j) o[j] = (float)s.Xoh[sp * 7 + j];
    float pes = s.pe[sp];
    #pragma unroll
    for (int hh = 0; hh < 4; ++hh) {
      int h = hb4 + hh;
      float acc = s.scA[av * 8 + h] + s.scZ[zv * 8 + h] + s.biasO8[h] + s.cb[h];
      acc = fmaf(pes, s.wsum8[h], acc);
      #pragma unroll
      for (int j = 0; j < 7; ++j) acc = fmaf(s.mHJ[h * 8 + j], o[j], acc);
      s.sc[h * SEQ + sp] = acc;
    }
  }
  __syncthreads();

  // ---- phase 5: softmax, wave-per-head (all 8 waves), in-place transpose ----
  {
    const int h = wid;
    float vals[4];
    float m = -1e30f;
    #pragma unroll
    for (int i = 0; i < 4; ++i) {
      vals[i] = s.sc[h * SEQ + lane * 4 + i];
      m = fmaxf(m, vals[i]);
    }
    #pragma unroll
    for (int off = 32; off > 0; off >>= 1) m = fmaxf(m, __shfl_xor(m, off, 64));
    float lsum = 0.f;
    #pragma unroll
    for (int i = 0; i < 4; ++i) { vals[i] = __expf(vals[i] - m); lsum += vals[i]; }
    #pragma unroll
    for (int off = 32; off > 0; off >>= 1) lsum += __shfl_xor(lsum, off, 64);
    float rinv = 1.0f / lsum;
    __syncthreads();   // everyone done reading sc before transpose-overwrite
    #pragma unroll
    for (int i = 0; i < 4; ++i) s.sc[(lane * 4 + i) * 8 + h] = vals[i] * rinv;
  }
  __syncthreads();

  // ---- phase 6a: histograms / moments, wave-per-head (all 8 waves) ----
  {
    const int h = wid;
    float att[4];
    #pragma unroll
    for (int i = 0; i < 4; ++i) att[i] = s.sc[(lane + 64 * i) * 8 + h];
    {
      float v = 0.f;
      #pragma unroll
      for (int i = 0; i < 4; ++i) v = fmaf(att[i], s.pe[lane + 64 * i], v);
      v = wave_allred(v);
      if (lane == 0) s.peAcc8[h] = v;
    }
    #pragma unroll
    for (int j = 0; j < 7; ++j) {
      float v = 0.f;
      #pragma unroll
      for (int i = 0; i < 4; ++i) v = fmaf(att[i], (float)s.Xoh[(lane + 64 * i) * 7 + j], v);
      v = wave_allred(v);
      if (lane == 0) s.oAcc[h * 7 + j] = v;
    }
    int code[4];
    #pragma unroll
    for (int i = 0; i < 4; ++i) code[i] = s.Xcode[lane + 64 * i];
    for (int a = 0; a < 9; ++a) {
      float v = 0.f;
      #pragma unroll
      for (int i = 0; i < 4; ++i) v += ((code[i] & 255) == a) ? att[i] : 0.f;
      v = wave_allred(v);
      if (lane == 0) s.attA[h * 9 + a] = v;
    }
    for (int z = 0; z < 20; ++z) {
      float v = 0.f;
      #pragma unroll
      for (int i = 0; i < 4; ++i) v += ((code[i] >> 8) == z) ? att[i] : 0.f;
      v = wave_allred(v);
      if (lane == 0) s.attZ[h * 20 + z] = v;
    }
  }
  __syncthreads();

  // ---- phase 6b: reconstruct u[h][d] (4 heads per half) ----
  {
    float acc[4];
    #pragma unroll
    for (int hh = 0; hh < 4; ++hh) acc[hh] = s.peAcc8[hb4 + hh];
    if (dd < 64) {
      for (int a = 0; a < 9; ++a) {
        float ev = embA[a * 65 + dd];
        #pragma unroll
        for (int hh = 0; hh < 4; ++hh) acc[hh] = fmaf(s.attA[(hb4 + hh) * 9 + a], ev, acc[hh]);
      }
    } else if (dd < 128) {
      int d2 = dd - 64;
      for (int z = 0; z < 20; ++z) {
        float ev = embZ[z * 65 + d2];
        #pragma unroll
        for (int hh = 0; hh < 4; ++hh) acc[hh] = fmaf(s.attZ[(hb4 + hh) * 20 + z], ev, acc[hh]);
      }
    } else {
      int kk = dd - 128;
      #pragma unroll
      for (int j = 0; j < 7; ++j) {
        float ov = l0w[kk * 7 + j];
        #pragma unroll
        for (int hh = 0; hh < 4; ++hh) acc[hh] = fmaf(s.oAcc[(hb4 + hh) * 7 + j], ov, acc[hh]);
      }
      #pragma unroll
      for (int hh = 0; hh < 4; ++hh) acc[hh] += l0b[kk];
    }
    #pragma unroll
    for (int hh = 0; hh < 4; ++hh) s.sc[(hb4 + hh) * DIM + dd] = acc[hh];
  }
  __syncthreads();

  // ---- phase 7: ao = Wv @ u + bv (8-row bursts; head = rowblock>>2) ----
  {
    #pragma unroll 1
    for (int t = 0; t < 4; ++t) {
      int rb = wid + 8 * t;
      int base = rb * 8;
      XH x = ldx8h(s.sc + (rb >> 2) * DIM, lane);
      W4 w = ldw4(qkv16 + (size_t)(2 * DIM + base) * 256, 256, lane);
      float p[4] = {};
      accum4(w, x, p);
      float u = fold4h(lane, p);
      int ro;
      if (burst_writer4(lane, ro)) s.ao[base + ro] = qkv_b[2 * DIM + base + ro] + u;
    }
  }
  __syncthreads();

  // ---- phase 8: tv = srcl + attn_o(ao); h1 = LN1(tv) (fused sum/sumsq) ----
  {
    XH x = ldx8h(s.ao, lane);
    #pragma unroll 1
    for (int t = 0; t < 4; ++t) {
      int base = (wid + 8 * t) * 8;
      W4 w = ldw4(ao16 + (size_t)base * 256, 256, lane);
      float p[4] = {};
      accum4(w, x, p);
      float u = fold4h(lane, p);
      int ro;
      if (burst_writer4(lane, ro)) {
        int rr = base + ro;
        s.qv[rr] = s.srcl[rr] + attn_o_b[rr] + u;
      }
    }
  }
  __syncthreads();
  {
    float tv = (tid < DIM) ? s.qv[tid] : 0.f;
    float A, B;
    block_sum8x2(tv, tv * tv, red, A, B);
    float mean = A * (1.0f / 256.0f);
    float var = B * (1.0f / 256.0f) - mean * mean;
    if (tid < DIM) s.h1[tid] = (tv - mean) / sqrtf(var + 1e-5f) * ln1_g[tid] + ln1_b[tid];
  }
  __syncthreads();

  // ---- phase 9: ffb = relu(ff1 @ h1 + b) (1024 rows, 16 bursts/wave) ----
  {
    XH x = ldx8h(s.h1, lane);
    #pragma unroll 1
    for (int t = 0; t < 16; ++t) {
      int base = (wid + 8 * t) * 8;
      W4 w = ldw4(ff116 + (size_t)base * 256, 256, lane);
      float p[4] = {};
      accum4(w, x, p);
      float u = fold4h(lane, p);
      int ro;
      if (burst_writer4(lane, ro)) {
        int rr = base + ro;
        s.sc[rr] = fmaxf(ff1_b[rr] + u, 0.f);
      }
    }
  }
  __syncthreads();

  // ---- phase 10: tv = h1 + ff2 @ ffb + b; h2 = LN2(tv) (K=1024, 4 chunks) ----
  {
    #pragma unroll 1
    for (int t = 0; t < 4; ++t) {
      int base = (wid + 8 * t) * 8;
      float p[4] = {};
      #pragma unroll 1
      for (int kc = 0; kc < 4; ++kc) {
        XH x = ldx8h(s.sc + kc * 256, lane);
        W4 w = ldw4(ff216 + (size_t)base * 1024 + kc * 256, 1024, lane);
        accum4(w, x, p);
      }
      float u = fold4h(lane, p);
      int ro;
      if (burst_writer4(lane, ro)) {
        int rr = base + ro;
        s.qv[rr] = s.h1[rr] + ff2_b[rr] + u;
      }
    }
  }
  __syncthreads();
  {
    float tv = (tid < DIM) ? s.qv[tid] : 0.f;
    float A, B;
    block_sum8x2(tv, tv * tv, red, A, B);
    float mean = A * (1.0f / 256.0f);
    float var = B * (1.0f / 256.0f) - mean * mean;
    if (tid < DIM) s.h2[tid] = (tv - mean) / sqrtf(var + 1e-5f) * ln2_g[tid] + ln2_b[tid];
  }
  __syncthreads();

  // ---- phase 11: xr = relu_w @ h2 + b ----
  {
    XH x = ldx8h(s.h2, lane);
    #pragma unroll 1
    for (int t = 0; t < 4; ++t) {
      int base = (wid + 8 * t) * 8;
      W4 w = ldw4(relu16 + (size_t)base * 256, 256, lane);
      float p[4] = {};
      accum4(w, x, p);
      float u = fold4h(lane, p);
      int ro;
      if (burst_writer4(lane, ro)) s.xr[base + ro] = relu_b[base + ro] + u;
    }
  }
  __syncthreads();

  // ---- phase 12: d1 = dT_w @ xr + b; dT = lindT . d1 + b ----
  {
    XH x = ldx8h(s.xr, lane);
    #pragma unroll 1
    for (int t = 0; t < 4; ++t) {
      int base = (wid + 8 * t) * 8;
      W4 w = ldw4(dT16 + (size_t)base * 256, 256, lane);
      float p[4] = {};
      accum4(w, x, p);
      float u = fold4h(lane, p);
      int ro;
      if (burst_writer4(lane, ro)) s.h1[base + ro] = dT_b[base + ro] + u;   // h1 = d1
    }
  }
  __syncthreads();
  float dTv;
  {
    float v = (tid < DIM) ? lindT_w[tid] * s.h1[tid] : 0.f;
    dTv = block_sum8(v, red) + lindT_b[0];
  }

  // ---- phase 13: zn path (f16 scalar rows, fold4) ----
  if (tid < DIM) { s.znin[1 + tid] = s.xr[tid]; s.fa[21 + tid] = s.xr[tid]; }
  if (tid == 0)  { s.znin[0] = dTv; s.fa[20] = dTv; }
  __syncthreads();
  float* z1 = s.sc + 1024;   // 257 floats
  for (int r0 = 4 * wid; r0 < 257; r0 += 4 * NW) {
    int nrow = 257 - r0; if (nrow > 4) nrow = 4;
    float p0 = 0, p1 = 0, p2 = 0, p3 = 0;
    for (int j = lane; j < 257; j += 64) {
      float xv = s.znin[j];
      const __fp16* wp = znh + (size_t)r0 * 257 + j;
      p0 = fmaf((float)wp[0], xv, p0);
      if (nrow > 1) p1 = fmaf((float)wp[257], xv, p1);
      if (nrow > 2) p2 = fmaf((float)wp[2 * 257], xv, p2);
      if (nrow > 3) p3 = fmaf((float)wp[3 * 257], xv, p3);
    }
    float u = fold4(lane, p0, p1, p2, p3);
    if ((lane & 15) == 0) {
      int g = lane >> 4;
      int rr = r0 + ((g & 1) << 1) + (g >> 1);
      if (rr < 257) z1[rr] = zn_b[rr] + u;
    }
  }
  __syncthreads();
  for (int r0 = 4 * wid; r0 < 20; r0 += 4 * NW) {
    float p0 = 0, p1 = 0, p2 = 0, p3 = 0;
    for (int j = lane; j < 257; j += 64) {
      float xv = z1[j];
      const float* wp = linzn_w + (size_t)r0 * 257 + j;
      p0 = fmaf(wp[0], xv, p0);
      p1 = fmaf(wp[257], xv, p1);
      p2 = fmaf(wp[2 * 257], xv, p2);
      p3 = fmaf(wp[3 * 257], xv, p3);
    }
    float u = fold4(lane, p0, p1, p2, p3);
    if ((lane & 15) == 0) {
      int g = lane >> 4;
      int rr = r0 + ((g & 1) << 1) + (g >> 1);
      if (rr < 20) { float v = linzn_b[rr] + u; s.znv[rr] = v; s.fa[rr] = v; }
    }
  }
  __syncthreads();

  // ---- phase 14: ac = linact @ act1 @ act0 @ fa (f16 scalar, fold4) ----
  float* a0v = s.sc + 1312;  // 277 floats
  for (int r0 = 4 * wid; r0 < 277; r0 += 4 * NW) {
    int nrow = 277 - r0; if (nrow > 4) nrow = 4;
    float p0 = 0, p1 = 0, p2 = 0, p3 = 0;
    for (int j = lane; j < 277; j += 64) {
      float xv = s.fa[j];
      const __fp16* wp = a0h + (size_t)r0 * 277 + j;
      p0 = fmaf((float)wp[0], xv, p0);
      if (nrow > 1) p1 = fmaf((float)wp[277], xv, p1);
      if (nrow > 2) p2 = fmaf((float)wp[2 * 277], xv, p2);
      if (nrow > 3) p3 = fmaf((float)wp[3 * 277], xv, p3);
    }
    float u = fold4(lane, p0, p1, p2, p3);
    if ((lane & 15) == 0) {
      int g = lane >> 4;
      int rr = r0 + ((g & 1) << 1) + (g >> 1);
      if (rr < 277) a0v[rr] = act0_b[rr] + u;
    }
  }
  __syncthreads();
  float* a1v = s.sc + 1024;  // z1 dead
  for (int r0 = 4 * wid; r0 < 277; r0 += 4 * NW) {
    int nrow = 277 - r0; if (nrow > 4) nrow = 4;
    float p0 = 0, p1 = 0, p2 = 0, p3 = 0;
    for (int j = lane; j < 277; j += 64) {
      float xv = a0v[j];
      const __fp16* wp = a1h + (size_t)r0 * 277 + j;
      p0 = fmaf((float)wp[0], xv, p0);
      if (nrow > 1) p1 = fmaf((float)wp[277], xv, p1);
      if (nrow > 2) p2 = fmaf((float)wp[2 * 277], xv, p2);
      if (nrow > 3) p3 = fmaf((float)wp[3 * 277], xv, p3);
    }
    float u = fold4(lane, p0, p1, p2, p3);
    if ((lane & 15) == 0) {
      int g = lane >> 4;
      int rr = r0 + ((g & 1) << 1) + (g >> 1);
      if (rr < 277) a1v[rr] = act1_b[rr] + u;
    }
  }
  __syncthreads();

  // ---- phase 15: outputs ----
  if (wid < 5) {
    const float* wr = linact_w + (size_t)wid * 277;
    float p = 0.f;
    for (int j = lane; j < 277; j += 64) p = fmaf(wr[j], a1v[j], p);
    #pragma unroll
    for (int off = 32; off > 0; off >>= 1) p += __shfl_xor(p, off, 64);
    if (lane == 0) out[b * 26 + 21 + wid] = linact_b[wid] + p;
  }
  if (tid == 0) out[b * 26] = dTv;
  if (tid < 20) out[b * 26 + 1 + tid] = s.znv[tid];
}

// ---------- launcher ----------

extern "C" void kernel_launch(void* const* d_in, const int* in_sizes, int n_in,
                              void* d_out, int out_size, void* d_ws, size_t ws_size,
                              hipStream_t stream) {
  (void)in_sizes; (void)n_in; (void)out_size; (void)ws_size;
  const int*   X        = (const int*)  d_in[0];
  const float* emb_act  = (const float*)d_in[1];
  const float* emb_zone = (const float*)d_in[2];
  const float* lin0_w   = (const float*)d_in[3];
  const float* lin0_b   = (const float*)d_in[4];
  const float* qkv_w    = (const float*)d_in[5];
  const float* qkv_b    = (const float*)d_in[6];
  const float* attn_o_w = (const float*)d_in[7];
  const float* attn_o_b = (const float*)d_in[8];
  const float* ln1_g    = (const float*)d_in[9];
  const float* ln1_b    = (const float*)d_in[10];
  const float* ff1_w    = (const float*)d_in[11];
  const float* ff1_b    = (const float*)d_in[12];
  const float* ff2_w    = (const float*)d_in[13];
  const float* ff2_b    = (const float*)d_in[14];
  const float* ln2_g    = (const float*)d_in[15];
  const float* ln2_b    = (const float*)d_in[16];
  const float* relu_w   = (const float*)d_in[17];
  const float* relu_b   = (const float*)d_in[18];
  const float* dT_w     = (const float*)d_in[19];
  const float* dT_b     = (const float*)d_in[20];
  const float* lindT_w  = (const float*)d_in[21];
  const float* lindT_b  = (const float*)d_in[22];
  const float* zn_w     = (const float*)d_in[23];
  const float* zn_b     = (const float*)d_in[24];
  const float* linzn_w  = (const float*)d_in[25];
  const float* linzn_b  = (const float*)d_in[26];
  const float* act0_w   = (const float*)d_in[27];
  const float* act0_b   = (const float*)d_in[28];
  const float* act1_w   = (const float*)d_in[29];
  const float* act1_b   = (const float*)d_in[30];
  const float* linact_w = (const float*)d_in[31];
  const float* linact_b = (const float*)d_in[32];
  float* out = (float*)d_out;
  ushort* w16 = (ushort*)d_ws;   // needs 2.41 MB of workspace

  cvt_weights<<<dim3((CVT_TOTAL + 511) / 512), dim3(512), 0, stream>>>(
      qkv_w, attn_o_w, ff1_w, ff2_w, relu_w, dT_w, zn_w, act0_w, act1_w, w16);

  nmstpp_fused<<<dim3(BATCH), dim3(NT), 0, stream>>>(
      X, emb_act, emb_zone, lin0_w, lin0_b, w16, qkv_b, attn_o_b,
      ln1_g, ln1_b, ff1_b, ff2_b, ln2_g, ln2_b,
      relu_b, dT_b, lindT_w, lindT_b, zn_b,
      linzn_w, linzn_b, act0_b, act1_b, linact_w, linact_b,
      out);
}

// Round 23
// 132.742 us; speedup vs baseline: 1.4619x; 1.4619x over previous
//
#include <hip/hip_runtime.h>
#include <math.h>

#define BATCH 512
#define SEQ   256
#define DIM   256
#define NHEAD 8
#define DFF   1024
#define NT    1024  // threads per block (16 waves)
#define NW    16    // waves per block

typedef unsigned short ushort;
typedef unsigned int   uint;
typedef __fp16 half2v __attribute__((ext_vector_type(2)));

// ---------- f16 weight image layout in d_ws (ushort units) ----------
#define OFF_QKV   0u          // 768*256
#define OFF_AO    196608u     // 256*256
#define OFF_FF1   262144u     // 1024*256
#define OFF_FF2   524288u     // 256*1024
#define OFF_RELU  786432u     // 256*256
#define OFF_DT    851968u     // 256*256
#define OFF_ZN    917504u     // 257*257
#define OFF_A0    983553u     // 277*277
#define OFF_A1    1060282u    // 277*277
#define OFF_KT    1137011u    // WkT: 256 d-rows x 256 k  (transposed Wk)
#define CVT_TOTAL 1202547u

// ---------- weight conversion kernel (runs every launch; deterministic) ----------
__global__ __launch_bounds__(512) void cvt_weights(
    const float* __restrict__ qkv, const float* __restrict__ ao,
    const float* __restrict__ ff1, const float* __restrict__ ff2,
    const float* __restrict__ relu, const float* __restrict__ dT,
    const float* __restrict__ zn, const float* __restrict__ a0,
    const float* __restrict__ a1, ushort* __restrict__ ws) {
  uint i = blockIdx.x * 512u + threadIdx.x;
  if (i >= CVT_TOTAL) return;
  float v;
  if (i >= OFF_KT) {
    uint idx = i - OFF_KT;
    uint d = idx >> 8, k = idx & 255u;
    v = qkv[(size_t)(256 + k) * 256 + d];   // WkT[d][k] = Wk[k][d]
  } else {
    const float* src; uint off;
    if      (i < OFF_AO)  { src = qkv;  off = OFF_QKV; }
    else if (i < OFF_FF1) { src = ao;   off = OFF_AO; }
    else if (i < OFF_FF2) { src = ff1;  off = OFF_FF1; }
    else if (i < OFF_RELU){ src = ff2;  off = OFF_FF2; }
    else if (i < OFF_DT)  { src = relu; off = OFF_RELU; }
    else if (i < OFF_ZN)  { src = dT;   off = OFF_DT; }
    else if (i < OFF_A0)  { src = zn;   off = OFF_ZN; }
    else if (i < OFF_A1)  { src = a0;   off = OFF_A0; }
    else                  { src = a1;   off = OFF_A1; }
    v = src[i - off];
  }
  __fp16 h = (__fp16)v;          // RNE
  union { __fp16 h; ushort u; } c; c.h = h;
  ws[i] = c.u;
}

// ---------- helpers ----------

__device__ __forceinline__ half2v u2h(uint u) {
  union { uint u; half2v h; } c; c.u = u; return c.h;
}

__device__ __forceinline__ float wave_allred(float v) {
  #pragma unroll
  for (int off = 32; off > 0; off >>= 1) v += __shfl_xor(v, off, 64);
  return v;
}

// Reduce 4 independent partials over a full wave. 16-lane group g = lane>>4
// holds value [0,2,1,3][g].
__device__ __forceinline__ float fold4(int lane, float p0, float p1, float p2, float p3) {
  float za = (lane & 32) ? p1 : p0;
  float ta = (lane & 32) ? p0 : p1;
  za += __shfl_xor(ta, 32, 64);
  float zb = (lane & 32) ? p3 : p2;
  float tb = (lane & 32) ? p2 : p3;
  zb += __shfl_xor(tb, 32, 64);
  float u = (lane & 16) ? zb : za;
  float t = (lane & 16) ? za : zb;
  u += __shfl_xor(t, 16, 64);
  u += __shfl_xor(u, 8, 64);
  u += __shfl_xor(u, 4, 64);
  u += __shfl_xor(u, 2, 64);
  u += __shfl_xor(u, 1, 64);
  return u;
}

// Reduce 4 partials WITHIN each 32-lane half (7 shuffles).
// 8-lane group g=(lane>>3)&3 holds value iv = ((g&1)<<1) | ((g>>1)&1).
__device__ __forceinline__ float fold4h(int lane, const float p[4]) {
  float z0 = (lane & 16) ? p[1] : p[0], y0 = (lane & 16) ? p[0] : p[1];
  z0 += __shfl_xor(y0, 16, 64);
  float z1 = (lane & 16) ? p[3] : p[2], y1 = (lane & 16) ? p[2] : p[3];
  z1 += __shfl_xor(y1, 16, 64);
  float u = (lane & 8) ? z1 : z0, t = (lane & 8) ? z0 : z1;
  u += __shfl_xor(t, 8, 64);
  u += __shfl_xor(u, 4, 64);
  u += __shfl_xor(u, 2, 64);
  u += __shfl_xor(u, 1, 64);
  return u;
}

// Writer lanes for a W4 burst: (lane&7)==0; row = base + (lane>>5)*4 + iv
__device__ __forceinline__ bool burst_writer4(int lane, int& row_off) {
  if (lane & 7) return false;
  int g = (lane >> 3) & 3;
  int iv = ((g & 1) << 1) | ((g >> 1) & 1);
  row_off = ((lane >> 5) << 2) + iv;
  return true;
}

struct XH { half2v h[4]; };   // 8 f16 activations, 4 VGPRs

__device__ __forceinline__ XH ldx8h(const float* __restrict__ x, int lane) {
  int k = (lane & 31) * 8;
  XH r;
  r.h[0] = __builtin_amdgcn_cvt_pkrtz(x[k],     x[k + 1]);
  r.h[1] = __builtin_amdgcn_cvt_pkrtz(x[k + 2], x[k + 3]);
  r.h[2] = __builtin_amdgcn_cvt_pkrtz(x[k + 4], x[k + 5]);
  r.h[3] = __builtin_amdgcn_cvt_pkrtz(x[k + 6], x[k + 7]);
  return r;
}

// 8 f16 weights (uint4) . 8 f16 activations via 4x v_dot2_f32_f16
__device__ __forceinline__ void accum1(uint4 w, const XH& x, float& p) {
  p = __builtin_amdgcn_fdot2(u2h(w.x), x.h[0], p, false);
  p = __builtin_amdgcn_fdot2(u2h(w.y), x.h[1], p, false);
  p = __builtin_amdgcn_fdot2(u2h(w.z), x.h[2], p, false);
  p = __builtin_amdgcn_fdot2(u2h(w.w), x.h[3], p, false);
}

struct W4 { uint4 w[4]; };   // one burst's weights: 4 rows x 16B (16 VGPRs)

// issue 4 row loads (each 32-lane half covers rows (lane>>5)*4 .. +3)
__device__ __forceinline__ W4 ldw4(const ushort* __restrict__ Wb, int ld, int lane) {
  const ushort* wp = Wb + (size_t)((lane >> 5) * 4) * ld + (lane & 31) * 8;
  W4 r;
  #pragma unroll
  for (int i = 0; i < 4; ++i) r.w[i] = *(const uint4*)(wp + (size_t)i * ld);
  return r;
}

__device__ __forceinline__ void accum4(const W4& w, const XH& x, float p[4]) {
  #pragma unroll
  for (int i = 0; i < 4; ++i) accum1(w.w[i], x, p[i]);
}

// block sum over 16 waves; ALL 1024 threads must call
__device__ __forceinline__ float block_sum16(float v, float* red) {
  #pragma unroll
  for (int off = 32; off > 0; off >>= 1) v += __shfl_xor(v, off, 64);
  __syncthreads();
  if ((threadIdx.x & 63) == 0) red[threadIdx.x >> 6] = v;
  __syncthreads();
  float s = 0.f;
  #pragma unroll
  for (int i = 0; i < NW; ++i) s += red[i];
  return s;
}

// fused dual block sum (sum, sumsq) -> one barrier pair instead of two
__device__ __forceinline__ void block_sum16x2(float a, float b2, float* red,
                                              float& A, float& B) {
  #pragma unroll
  for (int off = 32; off > 0; off >>= 1) {
    a  += __shfl_xor(a,  off, 64);
    b2 += __shfl_xor(b2, off, 64);
  }
  __syncthreads();
  if ((threadIdx.x & 63) == 0) {
    red[threadIdx.x >> 6] = a;
    red[NW + (threadIdx.x >> 6)] = b2;
  }
  __syncthreads();
  A = 0.f; B = 0.f;
  #pragma unroll
  for (int i = 0; i < NW; ++i) { A += red[i]; B += red[NW + i]; }
}

struct Buf {
  float sc[2048];     // w~ [d][h] -> scores [h][s] -> att [s][h] -> u [h][d] -> ffb -> z1/a0/a1
  float pe[SEQ];
  float srcl[DIM];
  float qv[DIM];      // q -> tv(LN1) -> tv(LN2)
  float ao[DIM];
  float h1[DIM];      // h1 -> d1
  float h2[DIM];
  float xr[DIM];
  float znin[260];
  float fa[280];
  float znv[20];
  float cb[8];
  float scA[9 * 8];
  float scZ[20 * 8];
  float mHJ[8 * 8];
  float biasO8[8];
  float wsum8[8];
  float attA[8 * 9];
  float attZ[8 * 20];
  float oAcc[8 * 7];
  float peAcc8[8];
  int   Xa[SEQ];
  int   Xz[SEQ];
  float Xo[SEQ * 7];
};

// ---------- fused kernel: ONE batch element per 1024-thread block ----------
// R20 configuration (best known: 133.2us). VGPR<=32 => 8 waves/SIMD;
// 512 blocks / 256 CUs = 2 blocks/CU x 16 waves = 32 waves/CU (85% occ).
// Grid size caps concurrency: NT=512 variants can't exceed 2 blocks/CU
// (R22 regression), W8 variants can't fit 32 VGPRs (R16/R17).

__global__ __launch_bounds__(NT, 8) void nmstpp_fused(
    const int*   __restrict__ X,
    const float* __restrict__ emb_act,
    const float* __restrict__ emb_zone,
    const float* __restrict__ lin0_w,
    const float* __restrict__ lin0_b,
    const ushort* __restrict__ w16,       // f16 weight image
    const float* __restrict__ qkv_b,
    const float* __restrict__ attn_o_b,
    const float* __restrict__ ln1_g, const float* __restrict__ ln1_b,
    const float* __restrict__ ff1_b,
    const float* __restrict__ ff2_b,
    const float* __restrict__ ln2_g, const float* __restrict__ ln2_b,
    const float* __restrict__ relu_b,
    const float* __restrict__ dT_b,
    const float* __restrict__ lindT_w,
    const float* __restrict__ lindT_b,
    const float* __restrict__ zn_b,
    const float* __restrict__ linzn_w,
    const float* __restrict__ linzn_b,
    const float* __restrict__ act0_b,
    const float* __restrict__ act1_b,
    const float* __restrict__ linact_w,
    const float* __restrict__ linact_b,
    float* __restrict__ out)
{
  const int tid  = threadIdx.x;
  const int wid  = tid >> 6;          // 0..15
  const int lane = tid & 63;
  const int b    = blockIdx.x;
  const int hq2  = (tid >> 8) * 2;    // quarter -> 2 heads
  const int dd   = tid & 255;         // channel/position for 256-wide split phases

  const ushort* qkv16  = w16 + OFF_QKV;
  const ushort* ao16   = w16 + OFF_AO;
  const ushort* ff116  = w16 + OFF_FF1;
  const ushort* ff216  = w16 + OFF_FF2;
  const ushort* relu16 = w16 + OFF_RELU;
  const ushort* dT16   = w16 + OFF_DT;
  const ushort* kt16   = w16 + OFF_KT;
  const __fp16* znh  = (const __fp16*)(w16 + OFF_ZN);
  const __fp16* a0h  = (const __fp16*)(w16 + OFF_A0);
  const __fp16* a1h  = (const __fp16*)(w16 + OFF_A1);

  __shared__ alignas(16) Buf s;
  __shared__ float embA[9 * 65];
  __shared__ float embZ[20 * 65];
  __shared__ float l0w[128 * 7];
  __shared__ float l0b[128];
  __shared__ float red[2 * NW];

  // ---- phase 0: stage tables + X / pe ----
  for (int i = tid; i < 9 * 64;  i += NT) embA[(i >> 6) * 65 + (i & 63)] = emb_act[i];
  for (int i = tid; i < 20 * 64; i += NT) embZ[(i >> 6) * 65 + (i & 63)] = emb_zone[i];
  for (int i = tid; i < 128 * 7; i += NT) l0w[i] = lin0_w[i];
  if (tid < 128) l0b[tid] = lin0_b[tid];
  if (tid < SEQ) {
    const int* xrow = X + (b * SEQ + tid) * 9;
    s.Xa[tid] = xrow[0];
    s.Xz[tid] = xrow[1];
    #pragma unroll
    for (int j = 0; j < 7; ++j) s.Xo[tid * 7 + j] = (float)xrow[2 + j];
    float ex  = (float)(2 * tid) / (float)SEQ;
    float ang = (float)b * exp2f(-ex * 6.643856189774724f);  // 100^-ex
    s.pe[tid] = ((tid & 1) == 0) ? __sinf(ang) : __cosf(ang);
  }
  __syncthreads();

  // ---- phase 1: src at last position ----
  if (tid < DIM) {
    int av = s.Xa[SEQ - 1], zv = s.Xz[SEQ - 1];
    float v;
    if (tid < 64)        v = embA[av * 65 + tid];
    else if (tid < 128)  v = embZ[zv * 65 + (tid - 64)];
    else {
      const float* lr = l0w + (tid - 128) * 7;
      float acc = l0b[tid - 128];
      #pragma unroll
      for (int j = 0; j < 7; ++j) acc = fmaf(lr[j], s.Xo[(SEQ - 1) * 7 + j], acc);
      v = acc;
    }
    s.srcl[tid] = v + s.pe[SEQ - 1];
  }
  __syncthreads();

  // ---- phase 2: q = Wq @ srcl + bq (2 x 8-row W4 bursts per wave) ----
  {
    XH x = ldx8h(s.srcl, lane);
    #pragma unroll 1
    for (int t = 0; t < 2; ++t) {
      int base = (wid + 16 * t) * 8;
      W4 w = ldw4(qkv16 + (size_t)base * 256, 256, lane);
      float p[4] = {};
      accum4(w, x, p);
      float u = fold4h(lane, p);
      int ro;
      if (burst_writer4(lane, ro)) s.qv[base + ro] = qkv_b[base + ro] + u;
    }
  }
  __syncthreads();

  // ---- phase 3: w~[d][h] via WkT bursts + segmented 4-lane fold ----
  {
    XH x = ldx8h(s.qv, lane);                 // q as f16
    const float inv = 0.17677669529663687f;  // 1/sqrt(32)
    #pragma unroll 1
    for (int t = 0; t < 2; ++t) {
      int base = (wid + 16 * t) * 8;          // 8 d-rows per burst
      W4 w = ldw4(kt16 + (size_t)base * 256, 256, lane);
      float p[4] = {};
      accum4(w, x, p);
      #pragma unroll
      for (int i = 0; i < 4; ++i) {
        p[i] += __shfl_xor(p[i], 1, 4);
        p[i] += __shfl_xor(p[i], 2, 4);
      }
      int sub = lane & 31;
      int h = sub >> 2, jj = sub & 3;
      int dbase = base + ((lane >> 5) << 2);
      s.sc[(dbase + jj) * 8 + h] = p[jj] * inv;
    }
  }
  __syncthreads();

  // ---- phase 3.5: collapse scores into lookup tables ----
  if (tid < 312) {
    if (tid < 296) {
      int h = tid / 37, k = tid - h * 37;
      if (k < 9) {
        float acc = 0.f;
        for (int c = 0; c < 64; ++c) acc = fmaf(s.sc[c * 8 + h], embA[k * 65 + c], acc);
        s.scA[k * 8 + h] = acc;
      } else if (k < 29) {
        int z = k - 9; float acc = 0.f;
        for (int c = 0; c < 64; ++c) acc = fmaf(s.sc[(64 + c) * 8 + h], embZ[z * 65 + c], acc);
        s.scZ[z * 8 + h] = acc;
      } else if (k < 36) {
        int j = k - 29; float acc = 0.f;
        for (int kk = 0; kk < 128; ++kk) acc = fmaf(s.sc[(128 + kk) * 8 + h], l0w[kk * 7 + j], acc);
        s.mHJ[h * 8 + j] = acc;
      } else {
        float acc = 0.f;
        for (int c = 0; c < 256; ++c) acc += s.sc[c * 8 + h];
        s.wsum8[h] = acc;
      }
    } else if (tid < 304) {
      int h = tid - 296; float acc = 0.f;
      for (int kk = 0; kk < 128; ++kk) acc = fmaf(s.sc[(128 + kk) * 8 + h], l0b[kk], acc);
      s.biasO8[h] = acc;
    } else {
      int h = tid - 304; float acc = 0.f;
      for (int c = 0; c < 32; ++c) acc += s.qv[h * 32 + c] * qkv_b[DIM + h * 32 + c];
      s.cb[h] = acc * 0.17677669529663687f;
    }
  }
  __syncthreads();

  // ---- phase 4: scores via tables (thread = (position, head-pair)) ----
  {
    const int sp = dd;
    int av = s.Xa[sp], zv = s.Xz[sp];
    float o[7];
    #pragma unroll
    for (int j = 0; j < 7; ++j) o[j] = s.Xo[sp * 7 + j];
    float pes = s.pe[sp];
    #pragma unroll
    for (int hh = 0; hh < 2; ++hh) {
      int h = hq2 + hh;
      float acc = s.scA[av * 8 + h] + s.scZ[zv * 8 + h] + s.biasO8[h] + s.cb[h];
      acc = fmaf(pes, s.wsum8[h], acc);
      #pragma unroll
      for (int j = 0; j < 7; ++j) acc = fmaf(s.mHJ[h * 8 + j], o[j], acc);
      s.sc[h * SEQ + sp] = acc;
    }
  }
  __syncthreads();

  // ---- phase 5: softmax, wave-per-head (waves 0-7), in-place transpose ----
  {
    const bool act = (wid < 8);
    const int h = wid & 7;
    float vals[4]; float rinv = 0.f;
    if (act) {
      float m = -1e30f;
      #pragma unroll
      for (int i = 0; i < 4; ++i) {
        vals[i] = s.sc[h * SEQ + lane * 4 + i];
        m = fmaxf(m, vals[i]);
      }
      #pragma unroll
      for (int off = 32; off > 0; off >>= 1) m = fmaxf(m, __shfl_xor(m, off, 64));
      float lsum = 0.f;
      #pragma unroll
      for (int i = 0; i < 4; ++i) { vals[i] = __expf(vals[i] - m); lsum += vals[i]; }
      #pragma unroll
      for (int off = 32; off > 0; off >>= 1) lsum += __shfl_xor(lsum, off, 64);
      rinv = 1.0f / lsum;
    }
    __syncthreads();   // everyone done reading sc before transpose-overwrite
    if (act) {
      #pragma unroll
      for (int i = 0; i < 4; ++i) s.sc[(lane * 4 + i) * 8 + h] = vals[i] * rinv;
    }
  }
  __syncthreads();

  // ---- phase 6a: histograms / moments, wave-per-head (waves 0-7) ----
  if (wid < 8) {
    const int h = wid;
    float att[4];
    #pragma unroll
    for (int i = 0; i < 4; ++i) att[i] = s.sc[(lane + 64 * i) * 8 + h];
    {
      float v = 0.f;
      #pragma unroll
      for (int i = 0; i < 4; ++i) v = fmaf(att[i], s.pe[lane + 64 * i], v);
      v = wave_allred(v);
      if (lane == 0) s.peAcc8[h] = v;
    }
    #pragma unroll
    for (int j = 0; j < 7; ++j) {
      float v = 0.f;
      #pragma unroll
      for (int i = 0; i < 4; ++i) v = fmaf(att[i], s.Xo[(lane + 64 * i) * 7 + j], v);
      v = wave_allred(v);
      if (lane == 0) s.oAcc[h * 7 + j] = v;
    }
    int code[4];
    #pragma unroll
    for (int i = 0; i < 4; ++i) {
      int sp = lane + 64 * i;
      code[i] = s.Xa[sp] | (s.Xz[sp] << 8);
    }
    for (int a = 0; a < 9; ++a) {
      float v = 0.f;
      #pragma unroll
      for (int i = 0; i < 4; ++i) v += ((code[i] & 255) == a) ? att[i] : 0.f;
      v = wave_allred(v);
      if (lane == 0) s.attA[h * 9 + a] = v;
    }
    for (int z = 0; z < 20; ++z) {
      float v = 0.f;
      #pragma unroll
      for (int i = 0; i < 4; ++i) v += ((code[i] >> 8) == z) ? att[i] : 0.f;
      v = wave_allred(v);
      if (lane == 0) s.attZ[h * 20 + z] = v;
    }
  }
  __syncthreads();

  // ---- phase 6b: reconstruct u[h][d] (2 heads per quarter) ----
  {
    float acc[2];
    #pragma unroll
    for (int hh = 0; hh < 2; ++hh) acc[hh] = s.peAcc8[hq2 + hh];
    if (dd < 64) {
      for (int a = 0; a < 9; ++a) {
        float ev = embA[a * 65 + dd];
        #pragma unroll
        for (int hh = 0; hh < 2; ++hh) acc[hh] = fmaf(s.attA[(hq2 + hh) * 9 + a], ev, acc[hh]);
      }
    } else if (dd < 128) {
      int d2 = dd - 64;
      for (int z = 0; z < 20; ++z) {
        float ev = embZ[z * 65 + d2];
        #pragma unroll
        for (int hh = 0; hh < 2; ++hh) acc[hh] = fmaf(s.attZ[(hq2 + hh) * 20 + z], ev, acc[hh]);
      }
    } else {
      int kk = dd - 128;
      #pragma unroll
      for (int j = 0; j < 7; ++j) {
        float ov = l0w[kk * 7 + j];
        #pragma unroll
        for (int hh = 0; hh < 2; ++hh) acc[hh] = fmaf(s.oAcc[(hq2 + hh) * 7 + j], ov, acc[hh]);
      }
      #pragma unroll
      for (int hh = 0; hh < 2; ++hh) acc[hh] += l0b[kk];
    }
    #pragma unroll
    for (int hh = 0; hh < 2; ++hh) s.sc[(hq2 + hh) * DIM + dd] = acc[hh];
  }
  __syncthreads();

  // ---- phase 7: ao = Wv @ u + bv (8-row bursts; head = rowblock>>2) ----
  {
    #pragma unroll 1
    for (int t = 0; t < 2; ++t) {
      int rb = wid + 16 * t;
      int base = rb * 8;
      XH x = ldx8h(s.sc + (rb >> 2) * DIM, lane);
      W4 w = ldw4(qkv16 + (size_t)(2 * DIM + base) * 256, 256, lane);
      float p[4] = {};
      accum4(w, x, p);
      float u = fold4h(lane, p);
      int ro;
      if (burst_writer4(lane, ro)) s.ao[base + ro] = qkv_b[2 * DIM + base + ro] + u;
    }
  }
  __syncthreads();

  // ---- phase 8: tv = srcl + attn_o(ao); h1 = LN1(tv) (fused sum/sumsq) ----
  {
    XH x = ldx8h(s.ao, lane);
    #pragma unroll 1
    for (int t = 0; t < 2; ++t) {
      int base = (wid + 16 * t) * 8;
      W4 w = ldw4(ao16 + (size_t)base * 256, 256, lane);
      float p[4] = {};
      accum4(w, x, p);
      float u = fold4h(lane, p);
      int ro;
      if (burst_writer4(lane, ro)) {
        int rr = base + ro;
        s.qv[rr] = s.srcl[rr] + attn_o_b[rr] + u;
      }
    }
  }
  __syncthreads();
  {
    float tv = (tid < DIM) ? s.qv[tid] : 0.f;
    float A, B;
    block_sum16x2(tv, tv * tv, red, A, B);
    float mean = A * (1.0f / 256.0f);
    float var = B * (1.0f / 256.0f) - mean * mean;
    if (tid < DIM) s.h1[tid] = (tv - mean) / sqrtf(var + 1e-5f) * ln1_g[tid] + ln1_b[tid];
  }
  __syncthreads();

  // ---- phase 9: ffb = relu(ff1 @ h1 + b) (1024 rows, 8 bursts/wave) ----
  {
    XH x = ldx8h(s.h1, lane);
    #pragma unroll 1
    for (int t = 0; t < 8; ++t) {
      int base = (wid + 16 * t) * 8;
      W4 w = ldw4(ff116 + (size_t)base * 256, 256, lane);
      float p[4] = {};
      accum4(w, x, p);
      float u = fold4h(lane, p);
      int ro;
      if (burst_writer4(lane, ro)) {
        int rr = base + ro;
        s.sc[rr] = fmaxf(ff1_b[rr] + u, 0.f);
      }
    }
  }
  __syncthreads();

  // ---- phase 10: tv = h1 + ff2 @ ffb + b; h2 = LN2(tv) (K=1024, 4 chunks) ----
  {
    #pragma unroll 1
    for (int t = 0; t < 2; ++t) {
      int base = (wid + 16 * t) * 8;
      float p[4] = {};
      #pragma unroll 1
      for (int kc = 0; kc < 4; ++kc) {
        XH x = ldx8h(s.sc + kc * 256, lane);
        W4 w = ldw4(ff216 + (size_t)base * 1024 + kc * 256, 1024, lane);
        accum4(w, x, p);
      }
      float u = fold4h(lane, p);
      int ro;
      if (burst_writer4(lane, ro)) {
        int rr = base + ro;
        s.qv[rr] = s.h1[rr] + ff2_b[rr] + u;
      }
    }
  }
  __syncthreads();
  {
    float tv = (tid < DIM) ? s.qv[tid] : 0.f;
    float A, B;
    block_sum16x2(tv, tv * tv, red, A, B);
    float mean = A * (1.0f / 256.0f);
    float var = B * (1.0f / 256.0f) - mean * mean;
    if (tid < DIM) s.h2[tid] = (tv - mean) / sqrtf(var + 1e-5f) * ln2_g[tid] + ln2_b[tid];
  }
  __syncthreads();

  // ---- phase 11: xr = relu_w @ h2 + b ----
  {
    XH x = ldx8h(s.h2, lane);
    #pragma unroll 1
    for (int t = 0; t < 2; ++t) {
      int base = (wid + 16 * t) * 8;
      W4 w = ldw4(relu16 + (size_t)base * 256, 256, lane);
      float p[4] = {};
      accum4(w, x, p);
      float u = fold4h(lane, p);
      int ro;
      if (burst_writer4(lane, ro)) s.xr[base + ro] = relu_b[base + ro] + u;
    }
  }
  __syncthreads();

  // ---- phase 12: d1 = dT_w @ xr + b; dT = lindT . d1 + b ----
  {
    XH x = ldx8h(s.xr, lane);
    #pragma unroll 1
    for (int t = 0; t < 2; ++t) {
      int base = (wid + 16 * t) * 8;
      W4 w = ldw4(dT16 + (size_t)base * 256, 256, lane);
      float p[4] = {};
      accum4(w, x, p);
      float u = fold4h(lane, p);
      int ro;
      if (burst_writer4(lane, ro)) s.h1[base + ro] = dT_b[base + ro] + u;   // h1 = d1
    }
  }
  __syncthreads();
  float dTv;
  {
    float v = (tid < DIM) ? lindT_w[tid] * s.h1[tid] : 0.f;
    dTv = block_sum16(v, red) + lindT_b[0];
  }

  // ---- phase 13: zn path (f16 scalar rows, fold4) ----
  if (tid < DIM) { s.znin[1 + tid] = s.xr[tid]; s.fa[21 + tid] = s.xr[tid]; }
  if (tid == 0)  { s.znin[0] = dTv; s.fa[20] = dTv; }
  __syncthreads();
  float* z1 = s.sc + 1024;   // 257 floats
  for (int r0 = 4 * wid; r0 < 257; r0 += 4 * NW) {
    int nrow = 257 - r0; if (nrow > 4) nrow = 4;
    float p0 = 0, p1 = 0, p2 = 0, p3 = 0;
    for (int j = lane; j < 257; j += 64) {
      float xv = s.znin[j];
      const __fp16* wp = znh + (size_t)r0 * 257 + j;
      p0 = fmaf((float)wp[0], xv, p0);
      if (nrow > 1) p1 = fmaf((float)wp[257], xv, p1);
      if (nrow > 2) p2 = fmaf((float)wp[2 * 257], xv, p2);
      if (nrow > 3) p3 = fmaf((float)wp[3 * 257], xv, p3);
    }
    float u = fold4(lane, p0, p1, p2, p3);
    if ((lane & 15) == 0) {
      int g = lane >> 4;
      int rr = r0 + ((g & 1) << 1) + (g >> 1);
      if (rr < 257) z1[rr] = zn_b[rr] + u;
    }
  }
  __syncthreads();
  for (int r0 = 4 * wid; r0 < 20; r0 += 4 * NW) {
    float p0 = 0, p1 = 0, p2 = 0, p3 = 0;
    for (int j = lane; j < 257; j += 64) {
      float xv = z1[j];
      const float* wp = linzn_w + (size_t)r0 * 257 + j;
      p0 = fmaf(wp[0], xv, p0);
      p1 = fmaf(wp[257], xv, p1);
      p2 = fmaf(wp[2 * 257], xv, p2);
      p3 = fmaf(wp[3 * 257], xv, p3);
    }
    float u = fold4(lane, p0, p1, p2, p3);
    if ((lane & 15) == 0) {
      int g = lane >> 4;
      int rr = r0 + ((g & 1) << 1) + (g >> 1);
      if (rr < 20) { float v = linzn_b[rr] + u; s.znv[rr] = v; s.fa[rr] = v; }
    }
  }
  __syncthreads();

  // ---- phase 14: ac = linact @ act1 @ act0 @ fa (f16 scalar, fold4) ----
  float* a0v = s.sc + 1312;  // 277 floats
  for (int r0 = 4 * wid; r0 < 277; r0 += 4 * NW) {
    int nrow = 277 - r0; if (nrow > 4) nrow = 4;
    float p0 = 0, p1 = 0, p2 = 0, p3 = 0;
    for (int j = lane; j < 277; j += 64) {
      float xv = s.fa[j];
      const __fp16* wp = a0h + (size_t)r0 * 277 + j;
      p0 = fmaf((float)wp[0], xv, p0);
      if (nrow > 1) p1 = fmaf((float)wp[277], xv, p1);
      if (nrow > 2) p2 = fmaf((float)wp[2 * 277], xv, p2);
      if (nrow > 3) p3 = fmaf((float)wp[3 * 277], xv, p3);
    }
    float u = fold4(lane, p0, p1, p2, p3);
    if ((lane & 15) == 0) {
      int g = lane >> 4;
      int rr = r0 + ((g & 1) << 1) + (g >> 1);
      if (rr < 277) a0v[rr] = act0_b[rr] + u;
    }
  }
  __syncthreads();
  float* a1v = s.sc + 1024;  // z1 dead
  for (int r0 = 4 * wid; r0 < 277; r0 += 4 * NW) {
    int nrow = 277 - r0; if (nrow > 4) nrow = 4;
    float p0 = 0, p1 = 0, p2 = 0, p3 = 0;
    for (int j = lane; j < 277; j += 64) {
      float xv = a0v[j];
      const __fp16* wp = a1h + (size_t)r0 * 277 + j;
      p0 = fmaf((float)wp[0], xv, p0);
      if (nrow > 1) p1 = fmaf((float)wp[277], xv, p1);
      if (nrow > 2) p2 = fmaf((float)wp[2 * 277], xv, p2);
      if (nrow > 3) p3 = fmaf((float)wp[3 * 277], xv, p3);
    }
    float u = fold4(lane, p0, p1, p2, p3);
    if ((lane & 15) == 0) {
      int g = lane >> 4;
      int rr = r0 + ((g & 1) << 1) + (g >> 1);
      if (rr < 277) a1v[rr] = act1_b[rr] + u;
    }
  }
  __syncthreads();

  // ---- phase 15: outputs ----
  if (wid < 5) {
    const float* wr = linact_w + (size_t)wid * 277;
    float p = 0.f;
    for (int j = lane; j < 277; j += 64) p = fmaf(wr[j], a1v[j], p);
    #pragma unroll
    for (int off = 32; off > 0; off >>= 1) p += __shfl_xor(p, off, 64);
    if (lane == 0) out[b * 26 + 21 + wid] = linact_b[wid] + p;
  }
  if (tid == 0) out[b * 26] = dTv;
  if (tid < 20) out[b * 26 + 1 + tid] = s.znv[tid];
}

// ---------- launcher ----------

extern "C" void kernel_launch(void* const* d_in, const int* in_sizes, int n_in,
                              void* d_out, int out_size, void* d_ws, size_t ws_size,
                              hipStream_t stream) {
  (void)in_sizes; (void)n_in; (void)out_size; (void)ws_size;
  const int*   X        = (const int*)  d_in[0];
  const float* emb_act  = (const float*)d_in[1];
  const float* emb_zone = (const float*)d_in[2];
  const float* lin0_w   = (const float*)d_in[3];
  const float* lin0_b   = (const float*)d_in[4];
  const float* qkv_w    = (const float*)d_in[5];
  const float* qkv_b    = (const float*)d_in[6];
  const float* attn_o_w = (const float*)d_in[7];
  const float* attn_o_b = (const float*)d_in[8];
  const float* ln1_g    = (const float*)d_in[9];
  const float* ln1_b    = (const float*)d_in[10];
  const float* ff1_w    = (const float*)d_in[11];
  const float* ff1_b    = (const float*)d_in[12];
  const float* ff2_w    = (const float*)d_in[13];
  const float* ff2_b    = (const float*)d_in[14];
  const float* ln2_g    = (const float*)d_in[15];
  const float* ln2_b    = (const float*)d_in[16];
  const float* relu_w   = (const float*)d_in[17];
  const float* relu_b   = (const float*)d_in[18];
  const float* dT_w     = (const float*)d_in[19];
  const float* dT_b     = (const float*)d_in[20];
  const float* lindT_w  = (const float*)d_in[21];
  const float* lindT_b  = (const float*)d_in[22];
  const float* zn_w     = (const float*)d_in[23];
  const float* zn_b     = (const float*)d_in[24];
  const float* linzn_w  = (const float*)d_in[25];
  const float* linzn_b  = (const float*)d_in[26];
  const float* act0_w   = (const float*)d_in[27];
  const float* act0_b   = (const float*)d_in[28];
  const float* act1_w   = (const float*)d_in[29];
  const float* act1_b   = (const float*)d_in[30];
  const float* linact_w = (const float*)d_in[31];
  const float* linact_b = (const float*)d_in[32];
  float* out = (float*)d_out;
  ushort* w16 = (ushort*)d_ws;   // needs 2.41 MB of workspace

  cvt_weights<<<dim3((CVT_TOTAL + 511) / 512), dim3(512), 0, stream>>>(
      qkv_w, attn_o_w, ff1_w, ff2_w, relu_w, dT_w, zn_w, act0_w, act1_w, w16);

  nmstpp_fused<<<dim3(BATCH), dim3(NT), 0, stream>>>(
      X, emb_act, emb_zone, lin0_w, lin0_b, w16, qkv_b, attn_o_b,
      ln1_g, ln1_b, ff1_b, ff2_b, ln2_g, ln2_b,
      relu_b, dT_b, lindT_w, lindT_b, zn_b,
      linzn_w, linzn_b, act0_b, act1_b, linact_w, linact_b,
      out);
}